// Round 7
// baseline (371.824 us; speedup 1.0000x reference)
//
#include <hip/hip_runtime.h>
#include <math.h>

#define BATCH 64
#define CD 256
#define NX 784
#define TRIU_N 32896

// LDS staging geometry (ushort elems)
#define BQS 2056          // k8-region stride in B region (256 rows * 8 + pad)
#define BARR (4*BQS)      // per-array (hi/lo) stride  = 8224
#define BBUF (2*BARR)     // one B double-buffer       = 16448
#define AOFF 32896        // ushort offset where A-bufs start (after 2 B-bufs)
#define AQS 1032          // k8-region stride in A region (128 rows * 8 + pad)
#define AARR (4*AQS)      // 4128
#define ABUF (2*AARR)     // 8256
#define HALF_ELEMS 65536  // ushort elems per (batch,half) half-matrix (hi+lo)

typedef unsigned short ushort_t;
typedef unsigned int uint_t;
typedef __attribute__((ext_vector_type(8))) short short8;
typedef __attribute__((ext_vector_type(16))) float floatx16;

__device__ __forceinline__ ushort_t f2bf(float x) {
    uint_t u = __float_as_uint(x);
    u += 0x7fffu + ((u >> 16) & 1u);
    return (ushort_t)(u >> 16);
}
__device__ __forceinline__ float bf2f(ushort_t h) {
    return __uint_as_float(((uint_t)h) << 16);
}
__device__ __forceinline__ void split2(float x, ushort_t& h, ushort_t& l) {
    h = f2bf(x);
    l = f2bf(x - bf2f(h));
}
__device__ __forceinline__ void pack8(const float* f, uint_t* hp, uint_t* lp) {
    #pragma unroll
    for (int i = 0; i < 4; ++i) {
        ushort_t h0, l0, h1, l1;
        split2(f[2*i], h0, l0);
        split2(f[2*i+1], h1, l1);
        hp[i] = (uint_t)h0 | ((uint_t)h1 << 16);
        lp[i] = (uint_t)l0 | ((uint_t)l1 << 16);
    }
}

// ---------------------------------------------------------------------------
// One BK=32 MFMA stage. Wave tile 64x64: rq2=wv>>2 rows, cp=wv&3 cols.
// 16 ds_read_b128 + 24 MFMA per wave.
template<bool SAME>
__device__ __forceinline__ void mfma_tile(const ushort_t* us, int buf, int half,
                                          int rq2, int cp, int khalf, int lr,
                                          floatx16 acc[2][2]) {
    #pragma unroll
    for (int ks = 0; ks < 2; ++ks) {
        const int c = ks * 2 + khalf;
        const ushort_t* kb = us + buf * BBUF + c * BQS;
        short8 aH[2], aL[2];
        #pragma unroll
        for (int rt = 0; rt < 2; ++rt) {
            if (SAME) {
                int ra = (half * 128 + rq2 * 64 + rt * 32 + lr) * 8;
                aH[rt] = *(const short8*)(kb + ra);
                aL[rt] = *(const short8*)(kb + BARR + ra);
            } else {
                const ushort_t* ka = us + AOFF + buf * ABUF + c * AQS
                                   + (rq2 * 64 + rt * 32 + lr) * 8;
                aH[rt] = *(const short8*)(ka);
                aL[rt] = *(const short8*)(ka + AARR);
            }
        }
        #pragma unroll
        for (int cq = 0; cq < 2; ++cq) {
            int rb = (cp * 64 + cq * 32 + lr) * 8;
            short8 bH = *(const short8*)(kb + rb);
            short8 bL = *(const short8*)(kb + BARR + rb);
            #pragma unroll
            for (int rt = 0; rt < 2; ++rt) {
                acc[rt][cq] = __builtin_amdgcn_mfma_f32_32x32x16_bf16(aH[rt], bH, acc[rt][cq], 0, 0, 0);
                acc[rt][cq] = __builtin_amdgcn_mfma_f32_32x32x16_bf16(aH[rt], bL, acc[rt][cq], 0, 0, 0);
                acc[rt][cq] = __builtin_amdgcn_mfma_f32_32x32x16_bf16(aL[rt], bH, acc[rt][cq], 0, 0, 0);
            }
        }
    }
}

// ---------------------------------------------------------------------------
// per-batch 2-block sync (R6-proven): release stores, bump, spin, acquire.
__device__ __forceinline__ void batch_sync(int* cnt, int tgt, int tid) {
    __syncthreads();
    if (tid == 0) {
        __threadfence();
        __hip_atomic_fetch_add(cnt, 1, __ATOMIC_RELAXED, __HIP_MEMORY_SCOPE_AGENT);
        while (__hip_atomic_load(cnt, __ATOMIC_RELAXED, __HIP_MEMORY_SCOPE_AGENT) < tgt)
            __builtin_amdgcn_s_sleep(4);
        __threadfence();
    }
    __syncthreads();
}

// ---------------------------------------------------------------------------
// One NS GEMM: out128x256 = Aown(128x256) . B(256x256)^T, B = own regs + partner global.
// MODE 0: O = 1.5*M - 0.5*acc  (regs + partner-half global write)
// MODE 1: O = it*(1.5*M - 0.5*it*acc)
// MODE 2: triu out = st*(1.5*M - 0.5*acc), no O
template<int MODE, bool SAME>
__device__ __forceinline__ void ns_gemm(
    ushort_t* us, float* fs,
    uint_t (&Amat)[64], uint_t (&Bown)[64], uint_t (&Mmat)[64], uint_t (&Omat)[64],
    const ushort_t* __restrict__ Pin, ushort_t* __restrict__ Pout,
    float* __restrict__ outT,
    float it, float st, int half, int tid, int lane, int wv)
{
    const int rq2 = wv >> 2, cp = wv & 3;
    const int khalf = lane >> 5, lr = lane & 31;
    const int row = tid >> 2, c4 = tid & 3;
    const int ph = half ^ 1;

    floatx16 acc[2][2];
    #pragma unroll
    for (int a = 0; a < 2; ++a)
        #pragma unroll
        for (int b = 0; b < 2; ++b)
            #pragma unroll
            for (int i = 0; i < 16; ++i) acc[a][b][i] = 0.f;

    auto dumps = [&](int s, int buf) {
        // partner half via async global->LDS (issue first, longest latency)
        #pragma unroll
        for (int j = 0; j < 2; ++j) {
            int id = wv * 2 + j;
            int arr = id >> 3, cc = (id >> 1) & 3, g = id & 1;
            const ushort_t* src = Pin + ((arr * 8 + s) * 4 + cc) * 1024 + g * 512 + lane * 8;
            ushort_t* dst = us + buf * BBUF + arr * BARR + cc * BQS + (ph * 128 + g * 64) * 8;
            __builtin_amdgcn_global_load_lds(
                (const __attribute__((address_space(1))) uint_t*)src,
                (__attribute__((address_space(3))) uint_t*)dst, 16, 0, 0);
        }
        // own B half from regs
        {
            uint4 hp = make_uint4(Bown[s*8+0], Bown[s*8+1], Bown[s*8+2], Bown[s*8+3]);
            uint4 lp = make_uint4(Bown[s*8+4], Bown[s*8+5], Bown[s*8+6], Bown[s*8+7]);
            int off = buf * BBUF + c4 * BQS + (half * 128 + row) * 8;
            *(uint4*)(us + off) = hp;
            *(uint4*)(us + off + BARR) = lp;
        }
        if (!SAME) {
            uint4 hp = make_uint4(Amat[s*8+0], Amat[s*8+1], Amat[s*8+2], Amat[s*8+3]);
            uint4 lp = make_uint4(Amat[s*8+4], Amat[s*8+5], Amat[s*8+6], Amat[s*8+7]);
            int off = AOFF + buf * ABUF + c4 * AQS + row * 8;
            *(uint4*)(us + off) = hp;
            *(uint4*)(us + off + AARR) = lp;
        }
    };

    dumps(0, 0);
    #pragma unroll
    for (int s = 0; s < 8; ++s) {
        __syncthreads();
        if (s < 7) dumps(s + 1, (s + 1) & 1);
        mfma_tile<SAME>(us, s & 1, half, rq2, cp, khalf, lr, acc);
    }

    // epilogue: bounce to fp32 LDS, then RSTORE readback
    __syncthreads();
    #pragma unroll
    for (int rt = 0; rt < 2; ++rt)
        #pragma unroll
        for (int cq = 0; cq < 2; ++cq)
            #pragma unroll
            for (int i = 0; i < 16; ++i) {
                int rl = (i & 3) + ((i >> 2) << 3) + (khalf << 2);
                fs[(rq2 * 64 + rt * 32 + rl) * 257 + cp * 64 + cq * 32 + lr] = acc[rt][cq][i];
            }
    __syncthreads();
    const int rg = half * 128 + row;
    #pragma unroll
    for (int s = 0; s < 8; ++s) {
        float v[8], m[8];
        #pragma unroll
        for (int j = 0; j < 8; ++j) v[j] = fs[row * 257 + s * 32 + c4 * 8 + j];
        #pragma unroll
        for (int j = 0; j < 8; ++j) {
            uint_t hw = Mmat[s * 8 + (j >> 1)], lw = Mmat[s * 8 + 4 + (j >> 1)];
            ushort_t hh = (j & 1) ? (ushort_t)(hw >> 16) : (ushort_t)(hw & 0xffff);
            ushort_t ll = (j & 1) ? (ushort_t)(lw >> 16) : (ushort_t)(lw & 0xffff);
            m[j] = bf2f(hh) + bf2f(ll);
        }
        if (MODE == 2) {
            int tb = rg * CD - (rg * (rg - 1)) / 2 - rg;
            #pragma unroll
            for (int j = 0; j < 8; ++j) {
                int c = s * 32 + c4 * 8 + j;
                float y = st * fmaf(1.5f, m[j], -0.5f * v[j]);
                if (c >= rg) outT[tb + c] = y;
            }
        } else {
            float y[8];
            #pragma unroll
            for (int j = 0; j < 8; ++j) {
                if (MODE == 1) y[j] = it * fmaf(1.5f, m[j], -0.5f * it * v[j]);
                else           y[j] = fmaf(1.5f, m[j], -0.5f * v[j]);
            }
            uint_t hp[4], lp[4];
            pack8(y, hp, lp);
            #pragma unroll
            for (int i = 0; i < 4; ++i) { Omat[s*8+i] = hp[i]; Omat[s*8+4+i] = lp[i]; }
            *(uint4*)(Pout + (s * 4 + c4) * 1024 + row * 8)       = make_uint4(hp[0], hp[1], hp[2], hp[3]);
            *(uint4*)(Pout + ((8 + s) * 4 + c4) * 1024 + row * 8) = make_uint4(lp[0], lp[1], lp[2], lp[3]);
        }
    }
}

// ---------------------------------------------------------------------------
// 128 blocks: (batch = bid&63, half = bid>>6). Whole pipeline in one kernel.
__global__ __launch_bounds__(512, 2)
void covns_k(const float* __restrict__ X, float* __restrict__ tr, int* __restrict__ cnt,
             ushort_t* __restrict__ P0, ushort_t* __restrict__ P1, ushort_t* __restrict__ P2,
             float* __restrict__ out) {
    __shared__ __align__(16) float fsmem[32896];   // 128.5 KB: staging bufs / fp32 bounce
    __shared__ float smean[256];
    __shared__ float sred[8];
    __shared__ float s_tr[2];
    ushort_t* us = (ushort_t*)fsmem;
    float* fs = fsmem;

    const int bid = blockIdx.x;
    const int bbx = bid & 63, half = bid >> 6, ph = half ^ 1;
    const int tid = threadIdx.x, lane = tid & 63, wv = tid >> 6;
    const int rq2 = wv >> 2, cp = wv & 3;
    const int khalf = lane >> 5, lr = lane & 31;
    const int row = tid >> 2, c4 = tid & 3;
    const float* Xb = X + (size_t)bbx * CD * NX;
    int* mycnt = cnt + bbx;

    uint_t M0[64], M1[64];   // two register-resident 128x256 split-bf16 row-panels

    // ---------------- Phase 1: Gram + means + trace -> M0 = Sigma ----------------
    floatx16 acc[2][2];
    #pragma unroll
    for (int a = 0; a < 2; ++a)
        #pragma unroll
        for (int b = 0; b < 2; ++b)
            #pragma unroll
            for (int i = 0; i < 16; ++i) acc[a][b][i] = 0.f;

    const int xrow = tid >> 1, xkc = tid & 1;
    float msum = 0.f;
    float4 cur[2][4];

    auto loadst = [&](int s, int d) {
        int gk = s * 32 + xkc * 16;
        if (gk < NX) {
            const float* p = Xb + (size_t)xrow * NX + gk;
            cur[d][0] = *(const float4*)p;
            cur[d][1] = *(const float4*)(p + 4);
            cur[d][2] = *(const float4*)(p + 8);
            cur[d][3] = *(const float4*)(p + 12);
        } else {
            float4 z = make_float4(0.f, 0.f, 0.f, 0.f);
            cur[d][0] = z; cur[d][1] = z; cur[d][2] = z; cur[d][3] = z;
        }
    };
    auto splitwr = [&](int d) {
        float f[16] = {cur[d][0].x, cur[d][0].y, cur[d][0].z, cur[d][0].w,
                       cur[d][1].x, cur[d][1].y, cur[d][1].z, cur[d][1].w,
                       cur[d][2].x, cur[d][2].y, cur[d][2].z, cur[d][2].w,
                       cur[d][3].x, cur[d][3].y, cur[d][3].z, cur[d][3].w};
        #pragma unroll
        for (int j = 0; j < 16; ++j) msum += f[j];
        #pragma unroll
        for (int cc = 0; cc < 2; ++cc) {
            uint_t hp[4], lp[4];
            pack8(f + cc * 8, hp, lp);
            int off = d * BBUF + (xkc * 2 + cc) * BQS + xrow * 8;
            *(uint4*)(us + off)        = make_uint4(hp[0], hp[1], hp[2], hp[3]);
            *(uint4*)(us + off + BARR) = make_uint4(lp[0], lp[1], lp[2], lp[3]);
        }
    };

    loadst(0, 0); splitwr(0); loadst(1, 1);
    for (int s = 0; s < 24; s += 2) {
        __syncthreads();
        loadst(s + 2, 0);
        splitwr(1);                       // stage s+1 -> buf1
        mfma_tile<true>(us, 0, half, rq2, cp, khalf, lr, acc);   // stage s
        __syncthreads();
        if (s + 3 <= 24) loadst(s + 3, 1);
        splitwr(0);                       // stage s+2 -> buf0
        mfma_tile<true>(us, 1, half, rq2, cp, khalf, lr, acc);   // stage s+1
    }
    __syncthreads();
    mfma_tile<true>(us, 0, half, rq2, cp, khalf, lr, acc);       // stage 24

    // means reduce
    __syncthreads();
    fs[xrow * 2 + xkc] = msum;
    __syncthreads();
    if (tid < 256) smean[tid] = (fs[tid * 2] + fs[tid * 2 + 1]) * (1.0f / NX);
    __syncthreads();

    // bounce + Sigma epilogue (-> M0, global set0, trace)
    #pragma unroll
    for (int rt = 0; rt < 2; ++rt)
        #pragma unroll
        for (int cq = 0; cq < 2; ++cq)
            #pragma unroll
            for (int i = 0; i < 16; ++i) {
                int rl = (i & 3) + ((i >> 2) << 3) + (khalf << 2);
                fs[(rq2 * 64 + rt * 32 + rl) * 257 + cp * 64 + cq * 32 + lr] = acc[rt][cq][i];
            }
    __syncthreads();
    {
        ushort_t* Pown = P0 + (size_t)((bbx << 1) + half) * HALF_ELEMS;
        const int rg = half * 128 + row;
        const float mr = smean[rg];
        float tsum = 0.f;
        #pragma unroll
        for (int s = 0; s < 8; ++s) {
            float y[8];
            #pragma unroll
            for (int j = 0; j < 8; ++j) {
                int c = s * 32 + c4 * 8 + j;
                float v = fs[row * 257 + c] * (1.0f / NX) - mr * smean[c];
                if (c == rg) tsum += v;
                y[j] = v;
            }
            uint_t hp[4], lp[4];
            pack8(y, hp, lp);
            #pragma unroll
            for (int i = 0; i < 4; ++i) { M0[s*8+i] = hp[i]; M0[s*8+4+i] = lp[i]; }
            *(uint4*)(Pown + (s * 4 + c4) * 1024 + row * 8)       = make_uint4(hp[0], hp[1], hp[2], hp[3]);
            *(uint4*)(Pown + ((8 + s) * 4 + c4) * 1024 + row * 8) = make_uint4(lp[0], lp[1], lp[2], lp[3]);
        }
        for (int off = 32; off; off >>= 1) tsum += __shfl_down(tsum, off, 64);
        if (lane == 0) sred[wv] = tsum;
        __syncthreads();
        if (tid == 0) {
            float t = 0.f;
            #pragma unroll
            for (int i = 0; i < 8; ++i) t += sred[i];
            atomicAdd(&tr[bbx], t);
        }
    }

    batch_sync(mycnt, 2, tid);
    if (tid == 0) {
        float t = __hip_atomic_load(&tr[bbx], __ATOMIC_RELAXED, __HIP_MEMORY_SCOPE_AGENT);
        s_tr[0] = 1.0f / t;
        s_tr[1] = sqrtf(t);
    }
    __syncthreads();
    const float it = s_tr[0], st = s_tr[1];

    // ---------------- Phase 2: 6-GEMM Newton-Schulz chain ----------------
    const size_t oh = (size_t)((bbx << 1) + half) * HALF_ELEMS;
    const size_t pih = (size_t)((bbx << 1) + ph) * HALF_ELEMS;

    // G1: Y1 = it*(1.5*Sig - 0.5*it*Sig^2)   M0 -> M1
    ns_gemm<1, true>(us, fs, M0, M0, M0, M1, P0 + pih, P1 + oh, nullptr,
                     it, 0.f, half, tid, lane, wv);
    batch_sync(mycnt, 4, tid);
    // G2: T1 = 1.5*Y1 - 0.5*Y1^2             M1 -> M0
    ns_gemm<0, true>(us, fs, M1, M1, M1, M0, P1 + pih, P2 + oh, nullptr,
                     0.f, 0.f, half, tid, lane, wv);
    batch_sync(mycnt, 6, tid);
    // G3: Y2 = 1.5*Y1 - 0.5*(Y1*T1)          A=M1,B=M0 -> M0
    ns_gemm<0, false>(us, fs, M1, M0, M1, M0, P2 + pih, P0 + oh, nullptr,
                      0.f, 0.f, half, tid, lane, wv);
    batch_sync(mycnt, 8, tid);
    // G4: T2 = 1.5*Y2 - 0.5*(Y1*Y2)          A=M1,B=M0,M=M0 -> M1
    ns_gemm<0, false>(us, fs, M1, M0, M0, M1, P0 + pih, P1 + oh, nullptr,
                      0.f, 0.f, half, tid, lane, wv);
    batch_sync(mycnt, 10, tid);
    // G5: T3 = 1.5*T2 - 0.5*T2^2             M1 -> M1
    ns_gemm<0, true>(us, fs, M1, M1, M1, M1, P1 + pih, P2 + oh, nullptr,
                     0.f, 0.f, half, tid, lane, wv);
    batch_sync(mycnt, 12, tid);
    // G6: out = st*(1.5*Y2 - 0.5*(Y2*T3)) triu   A=M0,B=M1,M=M0
    ns_gemm<2, false>(us, fs, M0, M1, M0, M0, P2 + pih, nullptr,
                      out + (size_t)bbx * TRIU_N, 0.f, st, half, tid, lane, wv);
}

// ---------------------------------------------------------------------------
extern "C" void kernel_launch(void* const* d_in, const int* in_sizes, int n_in,
                              void* d_out, int out_size, void* d_ws, size_t ws_size,
                              hipStream_t stream) {
    const float* x = (const float*)d_in[0];
    float* out = (float*)d_out;
    char* ws = (char*)d_ws;
    const size_t SETB = (size_t)BATCH * 2 * HALF_ELEMS * sizeof(ushort_t);  // 16 MB
    ushort_t* P0 = (ushort_t*)(ws);
    ushort_t* P1 = (ushort_t*)(ws + SETB);
    ushort_t* P2 = (ushort_t*)(ws + 2 * SETB);
    float* tr = (float*)(ws + 3 * SETB);          // 64 floats
    int* cnt = (int*)(tr + BATCH);                // 64 ints
    // total ws: 48 MB + 512 B

    hipMemsetAsync(tr, 0, BATCH * (sizeof(float) + sizeof(int)), stream);
    covns_k<<<128, 512, 0, stream>>>(x, tr, cnt, P0, P1, P2, out);
}